// Round 1
// baseline (544.266 us; speedup 1.0000x reference)
//
#include <hip/hip_runtime.h>
#include <hip/hip_bf16.h>

#define HC 64          // HEADS * C
#define D_IN 128
#define NEG_SLOPE 0.2f

// ---------------- zero ints ----------------
__global__ void k_zero(int* __restrict__ p, int n) {
    int i = blockIdx.x * blockDim.x + threadIdx.x;
    if (i < n) p[i] = 0;
}

// ---------------- projections: xl = x@Wl+bl, xr = x@Wr+br ----------------
// W fused quad layout in LDS: sW4[k4*128 + c] = float4(W[4k4+0..3][c'])
//   c in [0,64): W_l channel c ; c in [64,128): W_r channel c-64
__global__ __launch_bounds__(256, 2) void k_proj(
    const float* __restrict__ x,
    const float* __restrict__ Wl, const float* __restrict__ bl,
    const float* __restrict__ Wr, const float* __restrict__ br,
    float* __restrict__ xl, float* __restrict__ xr, int N) {
    __shared__ float sW[16384];   // 64 KB
    const int t = threadIdx.x;
    for (int idx = t; idx < 8192; idx += 256) {
        int k = idx >> 6;          // 0..127
        int c = idx & 63;
        sW[(((k >> 2) * 128) + c) * 4 + (k & 3)]      = Wl[idx];
        sW[(((k >> 2) * 128) + 64 + c) * 4 + (k & 3)] = Wr[idx];
    }
    __syncthreads();
    const int lane = t & 63;
    const int wave = t >> 6;
    const float blv = bl[lane];
    const float brv = br[lane];
    const float4* sW4 = (const float4*)sW;
    const int nquads = N >> 2;   // N divisible by 4 (100000)
    for (int q = blockIdx.x * 4 + wave; q < nquads; q += gridDim.x * 4) {
        const int i0 = q << 2;
        float accl[4], accr[4];
#pragma unroll
        for (int n = 0; n < 4; ++n) { accl[n] = blv; accr[n] = brv; }
        const float4* xq = (const float4*)(x + (size_t)i0 * D_IN);
#pragma unroll 4
        for (int k4 = 0; k4 < 32; ++k4) {
            float4 wl4 = sW4[k4 * 128 + lane];
            float4 wr4 = sW4[k4 * 128 + 64 + lane];
#pragma unroll
            for (int n = 0; n < 4; ++n) {
                float4 xv = xq[n * 32 + k4];   // wave-uniform broadcast load
                accl[n] += xv.x * wl4.x + xv.y * wl4.y + xv.z * wl4.z + xv.w * wl4.w;
                accr[n] += xv.x * wr4.x + xv.y * wr4.y + xv.z * wr4.z + xv.w * wr4.w;
            }
        }
#pragma unroll
        for (int n = 0; n < 4; ++n) {
            xl[(size_t)(i0 + n) * HC + lane] = accl[n];
            xr[(size_t)(i0 + n) * HC + lane] = accr[n];
        }
    }
}

// ---------------- degree histogram ----------------
__global__ void k_hist(const int* __restrict__ dst, int E, int* __restrict__ counts) {
    int e = blockIdx.x * blockDim.x + threadIdx.x;
    if (e < E) atomicAdd(&counts[dst[e]], 1);
}

// ---------------- exclusive scan (3 kernels) ----------------
// scan1: each block scans a 1024-element chunk (256 thr x 4), writes
// chunk-local exclusive prefix to row_off, chunk total to partials[b].
__global__ __launch_bounds__(256) void k_scan1(const int* __restrict__ counts, int N,
                                               int* __restrict__ row_off,
                                               int* __restrict__ partials) {
    __shared__ int lds[256];
    const int b = blockIdx.x;
    const int base = b * 1024;
    const int t = threadIdx.x;
    int c[4];
#pragma unroll
    for (int j = 0; j < 4; ++j) {
        int idx = base + t * 4 + j;
        c[j] = (idx < N) ? counts[idx] : 0;
    }
    int pre[4];
    pre[0] = 0; pre[1] = c[0]; pre[2] = pre[1] + c[1]; pre[3] = pre[2] + c[2];
    int tot = pre[3] + c[3];
    lds[t] = tot;
    __syncthreads();
    for (int off = 1; off < 256; off <<= 1) {
        int val = (t >= off) ? lds[t - off] : 0;
        __syncthreads();
        lds[t] += val;
        __syncthreads();
    }
    int texcl = (t > 0) ? lds[t - 1] : 0;
#pragma unroll
    for (int j = 0; j < 4; ++j) {
        int idx = base + t * 4 + j;
        if (idx < N) row_off[idx] = texcl + pre[j];
    }
    if (t == 255) partials[b] = lds[255];
}

// scan2: exclusive-scan the (<=256) block partials in one block
__global__ __launch_bounds__(256) void k_scan2(int* __restrict__ partials, int nb) {
    __shared__ int lds[256];
    const int t = threadIdx.x;
    lds[t] = (t < nb) ? partials[t] : 0;
    __syncthreads();
    for (int off = 1; off < 256; off <<= 1) {
        int val = (t >= off) ? lds[t - off] : 0;
        __syncthreads();
        lds[t] += val;
        __syncthreads();
    }
    int ex = (t > 0) ? lds[t - 1] : 0;
    if (t < nb) partials[t] = ex;
}

// scan3: add block offsets
__global__ void k_scan3(int* __restrict__ row_off, const int* __restrict__ partials, int N) {
    int idx = blockIdx.x * blockDim.x + threadIdx.x;
    if (idx < N) row_off[idx] += partials[idx >> 10];
}

// ---------------- scatter edges into CSR order (src only) ----------------
__global__ void k_scatter(const int* __restrict__ src, const int* __restrict__ dst, int E,
                          const int* __restrict__ row_off, int* __restrict__ fill,
                          int* __restrict__ sorted_src) {
    int e = blockIdx.x * blockDim.x + threadIdx.x;
    if (e < E) {
        int d = dst[e];
        int pos = row_off[d] + atomicAdd(&fill[d], 1);
        sorted_src[pos] = src[e];
    }
}

// ---------------- fused online-softmax aggregation + epilogue ----------------
// one wave per node; lane = channel (h = lane>>4, c = lane&15)
__global__ __launch_bounds__(256) void k_agg(
    const float* __restrict__ xl, const float* __restrict__ xr,
    const float* __restrict__ att, const float* __restrict__ bias,
    const float* __restrict__ Wh, const float* __restrict__ bh,
    const int* __restrict__ row_off, const int* __restrict__ counts,
    const int* __restrict__ sorted_src, float* __restrict__ out, int N) {
    const int wave = threadIdx.x >> 6;
    const int lane = threadIdx.x & 63;
    const int i = blockIdx.x * 4 + wave;
    if (i >= N) return;

    const float xri  = xr[(size_t)i * HC + lane];
    const float xli  = xl[(size_t)i * HC + lane];
    const float attl = att[lane];

    // self loop initializes the online softmax (every segment non-empty)
    float e0 = xli + xri;
    float v0 = (e0 >= 0.f) ? e0 : NEG_SLOPE * e0;
    float t0 = v0 * attl;
    t0 += __shfl_xor(t0, 1);
    t0 += __shfl_xor(t0, 2);
    t0 += __shfl_xor(t0, 4);
    t0 += __shfl_xor(t0, 8);   // per-head logit, broadcast in 16-lane group

    float m = t0;
    float s = 1.f;
    float acc = xli;

    const int beg = row_off[i];
    const int end = beg + counts[i];
    for (int p = beg; p < end; ++p) {
        int j = sorted_src[p];                       // wave-uniform
        float xlj = xl[(size_t)j * HC + lane];       // coalesced 256B gather
        float e = xlj + xri;
        float v = (e >= 0.f) ? e : NEG_SLOPE * e;
        float tt = v * attl;
        tt += __shfl_xor(tt, 1);
        tt += __shfl_xor(tt, 2);
        tt += __shfl_xor(tt, 4);
        tt += __shfl_xor(tt, 8);
        float nm = fmaxf(m, tt);
        float pe = __expf(tt - nm);
        float sc = __expf(m - nm);
        s = s * sc + pe;
        acc = acc * sc + pe * xlj;
        m = nm;
    }

    float o = acc / s + bias[lane];
    o = fmaxf(o, 0.f);                // ReLU
    float y = o * Wh[lane];           // head linear
    y += __shfl_xor(y, 1);
    y += __shfl_xor(y, 2);
    y += __shfl_xor(y, 4);
    y += __shfl_xor(y, 8);
    y += __shfl_xor(y, 16);
    y += __shfl_xor(y, 32);
    if (lane == 0) out[i] = y + bh[0];
}

// ---------------- launch ----------------
extern "C" void kernel_launch(void* const* d_in, const int* in_sizes, int n_in,
                              void* d_out, int out_size, void* d_ws, size_t ws_size,
                              hipStream_t stream) {
    const float* x   = (const float*)d_in[0];
    const int*   ei  = (const int*)d_in[1];
    const float* Wl  = (const float*)d_in[2];
    const float* bl  = (const float*)d_in[3];
    const float* Wr  = (const float*)d_in[4];
    const float* br  = (const float*)d_in[5];
    const float* att = (const float*)d_in[6];
    const float* bias= (const float*)d_in[7];
    const float* Wh  = (const float*)d_in[8];
    const float* bh  = (const float*)d_in[9];
    float* out = (float*)d_out;

    const int N = in_sizes[0] / D_IN;      // 100000
    const int E = in_sizes[1] / 2;         // 1600000
    const int* src = ei;
    const int* dst = ei + E;

    // workspace layout (256B aligned)
    auto align = [](size_t v) { return (v + 255) & ~(size_t)255; };
    char* ws = (char*)d_ws;
    size_t off = 0;
    float* xl       = (float*)(ws + off); off = align(off + (size_t)N * HC * 4);
    float* xr       = (float*)(ws + off); off = align(off + (size_t)N * HC * 4);
    int*   counts   = (int*)(ws + off);   off = align(off + (size_t)N * 4);
    int*   fill     = (int*)(ws + off);   off = align(off + (size_t)N * 4);
    int*   row_off  = (int*)(ws + off);   off = align(off + (size_t)N * 4);
    int*   partials = (int*)(ws + off);   off = align(off + 256 * 4);
    int*   sorted   = (int*)(ws + off);   off = align(off + (size_t)E * 4);
    (void)ws_size;

    // counts and fill are adjacent in intent but separately zeroed (simple)
    k_zero<<<(2 * N + 255) / 256, 256, 0, stream>>>(counts, N);
    k_zero<<<(N + 255) / 256, 256, 0, stream>>>(fill, N);

    k_proj<<<512, 256, 0, stream>>>(x, Wl, bl, Wr, br, xl, xr, N);

    k_hist<<<(E + 255) / 256, 256, 0, stream>>>(dst, E, counts);

    const int nb = (N + 1023) / 1024;     // 98 <= 256
    k_scan1<<<nb, 256, 0, stream>>>(counts, N, row_off, partials);
    k_scan2<<<1, 256, 0, stream>>>(partials, nb);
    k_scan3<<<(N + 255) / 256, 256, 0, stream>>>(row_off, partials, N);

    k_scatter<<<(E + 255) / 256, 256, 0, stream>>>(src, dst, E, row_off, fill, sorted);

    k_agg<<<(N + 3) / 4, 256, 0, stream>>>(xl, xr, att, bias, Wh, bh,
                                           row_off, counts, sorted, out, N);
}